// Round 4
// baseline (11838.539 us; speedup 1.0000x reference)
//
#include <hip/hip_runtime.h>

// ---------------------------------------------------------------------------
// SPCNNClassifier: conv1d(k5,p2)+BN+ReLU -> 3x BiLSTM(H=512) -> Linear(6) ->
// CRF NLL (mean over batch). B=16, T=1024, E=C=1024, H=512, L=6.
// R4: rec_kernel with interleaved MFMA A-rows (m=jj*4+g) so all 4 gates of a
// (j,batch) land in ONE lane's acc regs -> in-lane cell, single sync/step,
// no Ex-LDS transpose. Gates pre-transposed to G[t][j][b][4g] in gemm
// epilogue (coalesced 8B/lane prefetch). Hb stride 257 dw (conflict-free).
// Selective poll retry (only stale qwords reloaded).
// ---------------------------------------------------------------------------

typedef short bf16_t;
typedef __attribute__((ext_vector_type(8))) short bf16x8;
typedef __attribute__((ext_vector_type(4))) float f32x4;

__device__ __forceinline__ bf16_t f2b(float x) {
  unsigned u = __float_as_uint(x);
  unsigned r = (u + 0x7fffu + ((u >> 16) & 1u)) >> 16;   // RNE
  return (bf16_t)(unsigned short)r;
}
__device__ __forceinline__ float blo(unsigned u) { return __uint_as_float(u << 16); }
__device__ __forceinline__ float bhi(unsigned u) { return __uint_as_float(u & 0xffff0000u); }

// ---------------- converts ----------------

__global__ void embed_pad_k(const float* __restrict__ E, bf16_t* __restrict__ P) {
  size_t i4 = ((size_t)blockIdx.x * 256 + threadIdx.x) * 4;
  if (i4 >= 16ul * 1028 * 1024) return;
  int e = (int)(i4 & 1023);
  size_t rest = i4 >> 10;
  int tp = (int)(rest % 1028);
  int b  = (int)(rest / 1028);
  bf16_t o[4];
  if (tp >= 2 && tp < 1026) {
    const float4 v = *(const float4*)(E + (((size_t)b * 1024 + (tp - 2)) * 1024 + e));
    o[0] = f2b(v.x); o[1] = f2b(v.y); o[2] = f2b(v.z); o[3] = f2b(v.w);
  } else {
    o[0] = o[1] = o[2] = o[3] = 0;
  }
  *(uint2*)(P + i4) = *(const uint2*)o;
}

__global__ void convw_cvt_k(const float* __restrict__ S, bf16_t* __restrict__ D) {
  int idx = blockIdx.x * 256 + threadIdx.x;
  if (idx >= 1024 * 1024) return;
  int c = idx >> 10, e = idx & 1023;
  const float* s = S + (size_t)idx * 5;
#pragma unroll
  for (int kk = 0; kk < 5; kk++) D[(size_t)c * 5120 + kk * 1024 + e] = f2b(s[kk]);
}

__global__ void bnfold_k(const float* cb, const float* g, const float* be,
                         const float* mn, const float* vr, float* a, float* dd) {
  int c = blockIdx.x * 256 + threadIdx.x;
  if (c < 1024) {
    float s = g[c] * rsqrtf(vr[c] + 1e-5f);
    a[c] = s;
    dd[c] = (cb[c] - mn[c]) * s + be[c];
  }
}

__global__ void wihcvt_k(const float* __restrict__ S, bf16_t* __restrict__ D) {
  size_t i = ((size_t)blockIdx.x * 256 + threadIdx.x) * 4;
  if (i >= 3ul * 2 * 2048 * 1024) return;
  float4 v = *(const float4*)(S + i);
  bf16_t o[4] = {f2b(v.x), f2b(v.y), f2b(v.z), f2b(v.w)};
  *(uint2*)(D + i) = *(const uint2*)o;
}

// ---------------- gates GEMM: G[t][j][b][4g] = A[t*16+b][:] . W[g*512+j][:] + bias
// M=8192 (512 t x 16 b), N=2048 (4 g x 512 j), K=1024. Epilogue writes the
// rec-friendly transposed layout.
__global__ __launch_bounds__(256, 1) void gemm_gates(
    const bf16_t* __restrict__ A, const bf16_t* __restrict__ W,
    const float* __restrict__ bias0, const float* __restrict__ bias1,
    bf16_t* __restrict__ G) {
  const int tid = threadIdx.x;
  const int m0 = (blockIdx.x >> 4) * 128, n0 = (blockIdx.x & 15) * 128;
  __shared__ bf16_t As[128][72];
  __shared__ bf16_t Bs[128][72];
  const int wv = tid >> 6, ln = tid & 63;
  const int wm = (wv >> 1) * 64, wn = (wv & 1) * 64;
  const int lb = ln & 15, lq = ln >> 4;
  f32x4 acc[4][4] = {};
  for (int k0 = 0; k0 < 1024; k0 += 64) {
    __syncthreads();
#pragma unroll
    for (int i = 0; i < 4; i++) {
      int idx = tid + i * 256, r = idx >> 3, ch = idx & 7;
      *(uint4*)&As[r][ch * 8] = *(const uint4*)(A + (size_t)(m0 + r) * 1024 + k0 + ch * 8);
      *(uint4*)&Bs[r][ch * 8] = *(const uint4*)(W + (size_t)(n0 + r) * 1024 + k0 + ch * 8);
    }
    __syncthreads();
#pragma unroll
    for (int kk = 0; kk < 2; kk++) {
      bf16x8 af[4], bfr[4];
#pragma unroll
      for (int t = 0; t < 4; t++) {
        af[t]  = *(const bf16x8*)&As[wm + t * 16 + lb][kk * 32 + lq * 8];
        bfr[t] = *(const bf16x8*)&Bs[wn + t * 16 + lb][kk * 32 + lq * 8];
      }
#pragma unroll
      for (int mt = 0; mt < 4; mt++)
#pragma unroll
        for (int nt = 0; nt < 4; nt++)
          acc[mt][nt] = __builtin_amdgcn_mfma_f32_16x16x32_bf16(af[mt], bfr[nt], acc[mt][nt], 0, 0, 0);
    }
  }
#pragma unroll
  for (int mt = 0; mt < 4; mt++)
#pragma unroll
    for (int nt = 0; nt < 4; nt++) {
      int col = n0 + wn + nt * 16 + lb;          // g*512 + j
      int g = col >> 9, j = col & 511;
      float bs = bias0[col] + bias1[col];
#pragma unroll
      for (int r = 0; r < 4; r++) {
        int row = m0 + wm + mt * 16 + lq * 4 + r;  // t*16 + b
        int t = row >> 4, b = row & 15;
        G[(((size_t)t * 512 + j) * 16 + b) * 4 + g] = f2b(acc[mt][nt][r] + bs);
      }
    }
}

// ---------------- conv1d implicit GEMM + BN + ReLU
__global__ __launch_bounds__(256, 1) void conv_gemm(
    const bf16_t* __restrict__ EP, const bf16_t* __restrict__ Wc,
    const float* __restrict__ bn_a, const float* __restrict__ bn_d,
    bf16_t* __restrict__ X) {
  const int tid = threadIdx.x;
  const int m0 = (blockIdx.x >> 3) * 128, n0 = (blockIdx.x & 7) * 128;
  __shared__ bf16_t As[128][72];
  __shared__ bf16_t Bs[128][72];
  const int wv = tid >> 6, ln = tid & 63;
  const int wm = (wv >> 1) * 64, wn = (wv & 1) * 64;
  const int lb = ln & 15, lq = ln >> 4;
  f32x4 acc[4][4] = {};
  for (int kk = 0; kk < 5; kk++) {
    for (int k0 = 0; k0 < 1024; k0 += 64) {
      __syncthreads();
#pragma unroll
      for (int i = 0; i < 4; i++) {
        int idx = tid + i * 256, r = idx >> 3, ch = idx & 7;
        int m = m0 + r;
        const bf16_t* ap = EP + ((size_t)((m & 15) * 1028 + (m >> 4) + kk)) * 1024 + k0 + ch * 8;
        *(uint4*)&As[r][ch * 8] = *(const uint4*)ap;
        *(uint4*)&Bs[r][ch * 8] = *(const uint4*)(Wc + (size_t)(n0 + r) * 5120 + kk * 1024 + k0 + ch * 8);
      }
      __syncthreads();
#pragma unroll
      for (int kq = 0; kq < 2; kq++) {
        bf16x8 af[4], bfr[4];
#pragma unroll
        for (int t = 0; t < 4; t++) {
          af[t]  = *(const bf16x8*)&As[wm + t * 16 + lb][kq * 32 + lq * 8];
          bfr[t] = *(const bf16x8*)&Bs[wn + t * 16 + lb][kq * 32 + lq * 8];
        }
#pragma unroll
        for (int mt = 0; mt < 4; mt++)
#pragma unroll
          for (int nt = 0; nt < 4; nt++)
            acc[mt][nt] = __builtin_amdgcn_mfma_f32_16x16x32_bf16(af[mt], bfr[nt], acc[mt][nt], 0, 0, 0);
      }
    }
  }
#pragma unroll
  for (int mt = 0; mt < 4; mt++)
#pragma unroll
    for (int nt = 0; nt < 4; nt++) {
      int col = n0 + wn + nt * 16 + lb;
      float sa = bn_a[col], sd = bn_d[col];
#pragma unroll
      for (int r = 0; r < 4; r++) {
        int row = m0 + wm + mt * 16 + lq * 4 + r;
        float v = fmaxf(acc[mt][nt][r] * sa + sd, 0.f);
        X[(size_t)row * 1024 + col] = f2b(v);
      }
    }
}

// ---------------- persistent BiLSTM recurrence — in-lane cell, tagged exchange
// grid = 64 WGs: dir = blk>>5, j0 = (blk&31)*16. 256 thr = 4 waves; wave wv
// owns j in [j0+4wv, j0+4wv+4). A rows interleaved m=jj*4+g so lane (lq,lb)
// gets all 4 gates of (j=j0+4wv+lq, b=lb) in its 4 acc regs.
__global__ __launch_bounds__(256, 1) void rec_kernel(
    const float* __restrict__ Whh,               // [2][2048][512] f32
    const bf16_t* __restrict__ Gfw,              // [512 t][512 j][16 b][4 g]
    const bf16_t* __restrict__ Gbw,
    bf16_t* __restrict__ xout,                   // [1024][16][1024]
    unsigned long long* __restrict__ hstT,       // [2buf][2dir][16 b][256 pair]
    float* __restrict__ cst,                     // [2dir][16][512]
    int t0f, int t0b, int nsteps, int tag_base) {
  const int tid = threadIdx.x;
  const int d  = blockIdx.x >> 5;
  const int j0 = (blockIdx.x & 31) << 4;
  const int wv = tid >> 6;
  const int ln = tid & 63;
  const int lb = ln & 15;
  const int lq = ln >> 4;

  __shared__ bf16_t Hb[16][514];   // row stride 257 dw == 1 mod 32: conflict-free

  // A fragments, interleaved rows m = jj*4 + g (jj = m>>2, g = m&3).
  // lane's A-row m = lb -> Whh row = d*2048 + (lb&3)*512 + j0 + wv*4 + (lb>>2)
  bf16x8 afrag[16];
  {
    const float* wrow =
        Whh + ((size_t)(d * 2048 + (lb & 3) * 512 + j0 + wv * 4 + (lb >> 2))) * 512;
#pragma unroll
    for (int kk = 0; kk < 16; kk++) {
      const float* wp = wrow + kk * 32 + lq * 8;
      float4 va = *(const float4*)wp;
      float4 vb = *(const float4*)(wp + 4);
      bf16x8 fr;
      fr[0] = f2b(va.x); fr[1] = f2b(va.y); fr[2] = f2b(va.z); fr[3] = f2b(va.w);
      fr[4] = f2b(vb.x); fr[5] = f2b(vb.y); fr[6] = f2b(vb.z); fr[7] = f2b(vb.w);
      afrag[kk] = fr;
    }
  }
  // this lane's output coordinates
  const int jme = j0 + wv * 4 + lq;              // h unit
  float creg = cst[((size_t)d * 16 + lb) * 512 + jme];
  const bf16_t* G = (d == 0) ? Gfw : Gbw;

  // gate prefetch for s=0: 4 gates of (jme, lb), contiguous 8B
  uint2 gv;
  {
    const int trow = (d == 0) ? 0 : (nsteps - 1);
    gv = *(const uint2*)(G + (((size_t)trow * 512 + jme) * 16 + lb) * 4);
  }

  for (int s = 0; s < nsteps; s++) {
    const int rb = (s & 1) ^ 1, wb = s & 1;
    // tagged poll: wave wv owns batches 4wv..4wv+3 (1024 qwords), 16/lane
    {
      const unsigned long long* src =
          hstT + (((size_t)rb * 2 + d) * 16 + (wv << 2)) * 256;
      const unsigned expect = (unsigned)(tag_base + s);
      unsigned long long v[16];
#pragma unroll
      for (int i = 0; i < 16; i++)
        v[i] = __hip_atomic_load(src + i * 64 + ln, __ATOMIC_RELAXED, __HIP_MEMORY_SCOPE_AGENT);
      while (true) {
        bool ok = true;
#pragma unroll
        for (int i = 0; i < 16; i++) ok = ok && ((unsigned)(v[i] >> 32) == expect);
        if (__all(ok)) break;
#pragma unroll
        for (int i = 0; i < 16; i++)
          if ((unsigned)(v[i] >> 32) != expect)
            v[i] = __hip_atomic_load(src + i * 64 + ln, __ATOMIC_RELAXED, __HIP_MEMORY_SCOPE_AGENT);
      }
#pragma unroll
      for (int i = 0; i < 16; i++) {
        int idx = i * 64 + ln;                   // (local batch)*256 + pair
        *(unsigned*)&Hb[(wv << 2) + (idx >> 8)][(idx & 255) * 2] = (unsigned)v[i];
      }
    }
    __syncthreads();
    const int t = (d == 0) ? (t0f + s) : (t0b + nsteps - 1 - s);
    f32x4 acc0, acc1;
    acc0[0] = blo(gv.x); acc0[1] = bhi(gv.x); acc0[2] = blo(gv.y); acc0[3] = bhi(gv.y);
    acc1[0] = 0.f; acc1[1] = 0.f; acc1[2] = 0.f; acc1[3] = 0.f;
#pragma unroll
    for (int kk = 0; kk < 8; kk++) {
      bf16x8 b0 = *(const bf16x8*)&Hb[lb][(2 * kk) * 32 + lq * 8];
      bf16x8 b1 = *(const bf16x8*)&Hb[lb][(2 * kk + 1) * 32 + lq * 8];
      acc0 = __builtin_amdgcn_mfma_f32_16x16x32_bf16(afrag[2 * kk], b0, acc0, 0, 0, 0);
      acc1 = __builtin_amdgcn_mfma_f32_16x16x32_bf16(afrag[2 * kk + 1], b1, acc1, 0, 0, 0);
    }
    // prefetch next step's gates (independent of h)
    if (s + 1 < nsteps) {
      const int trn = (d == 0) ? (s + 1) : (nsteps - 2 - s);
      gv = *(const uint2*)(G + (((size_t)trn * 512 + jme) * 16 + lb) * 4);
    }
    // in-lane cell update: acc{0}+acc{1} = (i,f,g,o) for (jme, lb)
    float gi = acc0[0] + acc1[0], gf = acc0[1] + acc1[1];
    float gg = acc0[2] + acc1[2], go = acc0[3] + acc1[3];
    float si = 1.f / (1.f + expf(-gi));
    float sf = 1.f / (1.f + expf(-gf));
    float so = 1.f / (1.f + expf(-go));
    creg = sf * creg + si * tanhf(gg);
    float h = so * tanhf(creg);
    bf16_t hb = f2b(h);
    // pack pair (jme even, jme+1) across lanes ln, ln+16; lq even stores
    {
      unsigned hu = (unsigned)(unsigned short)hb;
      unsigned hp = (unsigned)__shfl_down((int)hu, 16, 64);
      if ((lq & 1) == 0) {
        unsigned data = hu | (hp << 16);
        unsigned long long val =
            ((unsigned long long)(unsigned)(tag_base + s + 1) << 32) | data;
        unsigned long long* dst =
            hstT + (((size_t)wb * 2 + d) * 16 + lb) * 256 + (jme >> 1);
        __hip_atomic_store(dst, val, __ATOMIC_RELAXED, __HIP_MEMORY_SCOPE_AGENT);
      }
    }
    xout[((size_t)t * 16 + lb) * 1024 + d * 512 + jme] = hb;
  }
  cst[((size_t)d * 16 + lb) * 512 + jme] = creg;
}

// ---------------- classifier
__global__ void cls_kernel(const bf16_t* __restrict__ X, const float* __restrict__ Wc,
                           const float* __restrict__ bc, float* __restrict__ Lg) {
  int wv = threadIdx.x >> 6, ln = threadIdx.x & 63;
  size_t m = (size_t)blockIdx.x * 4 + wv;
  const bf16_t* xr = X + m * 1024 + ln * 16;
  uint4 v0 = *(const uint4*)xr;
  uint4 v1 = *(const uint4*)(xr + 8);
  float xv[16];
  const unsigned* p0 = (const unsigned*)&v0;
  const unsigned* p1 = (const unsigned*)&v1;
#pragma unroll
  for (int i = 0; i < 4; i++) { xv[2 * i] = blo(p0[i]); xv[2 * i + 1] = bhi(p0[i]); }
#pragma unroll
  for (int i = 0; i < 4; i++) { xv[8 + 2 * i] = blo(p1[i]); xv[8 + 2 * i + 1] = bhi(p1[i]); }
#pragma unroll
  for (int l = 0; l < 6; l++) {
    const float* wr = Wc + l * 1024 + ln * 16;
    float p = 0.f;
#pragma unroll
    for (int i = 0; i < 16; i++) p += xv[i] * wr[i];
#pragma unroll
    for (int off = 32; off; off >>= 1) p += __shfl_xor(p, off, 64);
    if (ln == 0) Lg[m * 6 + l] = p + bc[l];
  }
}

// ---------------- CRF NLL
__global__ void crf_kernel(const float* __restrict__ Lg, const int* __restrict__ attn,
                           const int* __restrict__ labels, const float* __restrict__ start,
                           const float* __restrict__ endw, const float* __restrict__ trans,
                           float* __restrict__ out) {
  int b = blockIdx.x, ln = threadIdx.x;
  __shared__ float str[36];
  __shared__ int tg[1024];
  __shared__ unsigned char mk[1024];
  if (ln < 36) str[ln] = trans[ln];
  for (int t = ln; t < 1024; t += 64) {
    int lab = labels[b * 1024 + t];
    mk[t] = (unsigned char)((attn[b * 1024 + t] != 0) && (lab != -100));
    tg[t] = (lab == -100) ? 0 : lab;
  }
  __syncthreads();
  int j = ln;
  bool act = j < 6;
  float alpha = act ? (start[j] + Lg[(size_t)b * 6 + j]) : -1e30f;
  for (int t = 1; t < 1024; t++) {
    float vv[6], mx = -1e30f;
#pragma unroll
    for (int i = 0; i < 6; i++) {
      float ai = __shfl(alpha, i, 64);
      float v = ai + str[i * 6 + (act ? j : 0)];
      vv[i] = v;
      mx = fmaxf(mx, v);
    }
    float sm = 0.f;
#pragma unroll
    for (int i = 0; i < 6; i++) sm += expf(vv[i] - mx);
    float na = mx + logf(sm) + (act ? Lg[((size_t)t * 16 + b) * 6 + j] : 0.f);
    if (mk[t] && act) alpha = na;
  }
  float z = act ? (alpha + endw[j]) : -1e30f;
  float zm = z;
#pragma unroll
  for (int i = 0; i < 6; i++) zm = fmaxf(zm, __shfl(z, i, 64));
  float zs = act ? expf(z - zm) : 0.f;
  float tot = 0.f;
#pragma unroll
  for (int i = 0; i < 6; i++) tot += __shfl(zs, i, 64);
  float den = zm + logf(tot);
  if (ln == 0) {
    float score = start[tg[0]] + Lg[(size_t)b * 6 + tg[0]];
    int prev = tg[0];
    for (int t = 1; t < 1024; t++) {
      if (mk[t]) {
        score += str[prev * 6 + tg[t]] + Lg[((size_t)t * 16 + b) * 6 + tg[t]];
        prev = tg[t];
      }
    }
    score += endw[prev];
    atomicAdd(out, (den - score) * (1.0f / 16.0f));
  }
}

// ---------------------------------------------------------------------------
extern "C" void kernel_launch(void* const* d_in, const int* in_sizes, int n_in,
                              void* d_out, int out_size, void* d_ws, size_t ws_size,
                              hipStream_t stream) {
  const float* emb    = (const float*)d_in[0];
  const int*   attn   = (const int*)d_in[1];
  const int*   labels = (const int*)d_in[2];
  const float* convw  = (const float*)d_in[3];
  const float* convb  = (const float*)d_in[4];
  const float* bng    = (const float*)d_in[5];
  const float* bnb    = (const float*)d_in[6];
  const float* bnm    = (const float*)d_in[7];
  const float* bnv    = (const float*)d_in[8];
  const float* wih    = (const float*)d_in[9];
  const float* whh    = (const float*)d_in[10];
  const float* bih    = (const float*)d_in[11];
  const float* bhh    = (const float*)d_in[12];
  const float* clsw   = (const float*)d_in[13];
  const float* clsb   = (const float*)d_in[14];
  const float* crfs   = (const float*)d_in[15];
  const float* crfe   = (const float*)d_in[16];
  const float* crft   = (const float*)d_in[17];
  (void)in_sizes; (void)n_in; (void)out_size; (void)ws_size;

  char* w = (char*)d_ws;
  auto alloc = [&](size_t bytes) { char* p = w; w += (bytes + 255) & ~(size_t)255; return p; };
  bf16_t* emb_pad = (bf16_t*)alloc(16ul * 1028 * 1024 * 2);
  bf16_t* wconv   = (bf16_t*)alloc(1024ul * 5120 * 2);
  float*  bn_a    = (float*)alloc(4096);
  float*  bn_d    = (float*)alloc(4096);
  bf16_t* wihb    = (bf16_t*)alloc(3ul * 2 * 2048 * 1024 * 2);
  bf16_t* xA      = (bf16_t*)alloc(16384ul * 1024 * 2);
  bf16_t* xB      = (bf16_t*)alloc(16384ul * 1024 * 2);
  bf16_t* gfw     = (bf16_t*)alloc(512ul * 512 * 16 * 4 * 2);   // G layout
  bf16_t* gbw     = (bf16_t*)alloc(512ul * 512 * 16 * 4 * 2);
  unsigned long long* hstT = (unsigned long long*)alloc(2ul * 2 * 16 * 256 * 8);
  float*  cst     = (float*)alloc(2ul * 16 * 512 * 4);
  float*  lgt     = (float*)alloc(16384ul * 6 * 4);

  hipMemsetAsync(d_out, 0, 4, stream);

  embed_pad_k<<<16448, 256, 0, stream>>>(emb, emb_pad);
  convw_cvt_k<<<4096, 256, 0, stream>>>(convw, wconv);
  bnfold_k<<<4, 256, 0, stream>>>(convb, bng, bnb, bnm, bnv, bn_a, bn_d);
  wihcvt_k<<<12288, 256, 0, stream>>>(wih, wihb);

  conv_gemm<<<128 * 8, 256, 0, stream>>>(emb_pad, wconv, bn_a, bn_d, xA);

  bf16_t* xin = xA;
  bf16_t* xout = xB;
  for (int l = 0; l < 3; l++) {
    hipMemsetAsync(hstT, 0, 2ul * 2 * 16 * 256 * 8, stream);
    hipMemsetAsync(cst, 0, 2ul * 16 * 512 * 4, stream);
    for (int c = 0; c < 2; c++) {
      int t0f = c * 512, t0b = (1 - c) * 512;
      gemm_gates<<<64 * 16, 256, 0, stream>>>(
          xin + (size_t)t0f * 16 * 1024, wihb + ((size_t)l * 2 + 0) * 2048 * 1024,
          bih + (l * 2 + 0) * 2048, bhh + (l * 2 + 0) * 2048, gfw);
      gemm_gates<<<64 * 16, 256, 0, stream>>>(
          xin + (size_t)t0b * 16 * 1024, wihb + ((size_t)l * 2 + 1) * 2048 * 1024,
          bih + (l * 2 + 1) * 2048, bhh + (l * 2 + 1) * 2048, gbw);
      rec_kernel<<<64, 256, 0, stream>>>(whh + (size_t)l * 2 * 2048 * 512,
                                         gfw, gbw, xout, hstT, cst, t0f, t0b, 512, c * 512);
    }
    bf16_t* tmp = xin; xin = xout; xout = tmp;
  }

  cls_kernel<<<4096, 256, 0, stream>>>(xin, clsw, clsb, lgt);
  crf_kernel<<<16, 64, 0, stream>>>(lgt, attn, labels, crfs, crfe, crft, (float*)d_out);
}

// Round 5
// 9004.790 us; speedup vs baseline: 1.3147x; 1.3147x over previous
//
#include <hip/hip_runtime.h>

// ---------------------------------------------------------------------------
// SPCNNClassifier: conv1d(k5,p2)+BN+ReLU -> 3x BiLSTM(H=512) -> Linear(6) ->
// CRF NLL (mean over batch). B=16, T=1024, E=C=1024, H=512, L=6.
// R5 = R3 structure (wave-per-gate MFMA, Ex-LDS cell) + memory-path fixes:
//  - gates re-laid per-WG-contiguous G[t][jblk][g][j'][b]; rec copies its 2KB
//    slice to LDS each step, pipelined 1 ahead, issued before the poll.
//  - hstT [pair][b] + cell mapping cb=tid&15 -> coalesced 128B h-stores.
//  - xout LDS-buffered, flushed every 16 steps (off the per-step vmcnt path).
//  - Hb stride 522 elems (261 dw == 5 mod 32): <=3-way LDS banks.
// ---------------------------------------------------------------------------

typedef short bf16_t;
typedef __attribute__((ext_vector_type(8))) short bf16x8;
typedef __attribute__((ext_vector_type(4))) float f32x4;

__device__ __forceinline__ bf16_t f2b(float x) {
  unsigned u = __float_as_uint(x);
  unsigned r = (u + 0x7fffu + ((u >> 16) & 1u)) >> 16;   // RNE
  return (bf16_t)(unsigned short)r;
}
__device__ __forceinline__ float b2f(bf16_t b) {
  return __uint_as_float(((unsigned)(unsigned short)b) << 16);
}
__device__ __forceinline__ float blo(unsigned u) { return __uint_as_float(u << 16); }
__device__ __forceinline__ float bhi(unsigned u) { return __uint_as_float(u & 0xffff0000u); }

// ---------------- converts ----------------

__global__ void embed_pad_k(const float* __restrict__ E, bf16_t* __restrict__ P) {
  size_t i4 = ((size_t)blockIdx.x * 256 + threadIdx.x) * 4;
  if (i4 >= 16ul * 1028 * 1024) return;
  int e = (int)(i4 & 1023);
  size_t rest = i4 >> 10;
  int tp = (int)(rest % 1028);
  int b  = (int)(rest / 1028);
  bf16_t o[4];
  if (tp >= 2 && tp < 1026) {
    const float4 v = *(const float4*)(E + (((size_t)b * 1024 + (tp - 2)) * 1024 + e));
    o[0] = f2b(v.x); o[1] = f2b(v.y); o[2] = f2b(v.z); o[3] = f2b(v.w);
  } else {
    o[0] = o[1] = o[2] = o[3] = 0;
  }
  *(uint2*)(P + i4) = *(const uint2*)o;
}

__global__ void convw_cvt_k(const float* __restrict__ S, bf16_t* __restrict__ D) {
  int idx = blockIdx.x * 256 + threadIdx.x;
  if (idx >= 1024 * 1024) return;
  int c = idx >> 10, e = idx & 1023;
  const float* s = S + (size_t)idx * 5;
#pragma unroll
  for (int kk = 0; kk < 5; kk++) D[(size_t)c * 5120 + kk * 1024 + e] = f2b(s[kk]);
}

__global__ void bnfold_k(const float* cb, const float* g, const float* be,
                         const float* mn, const float* vr, float* a, float* dd) {
  int c = blockIdx.x * 256 + threadIdx.x;
  if (c < 1024) {
    float s = g[c] * rsqrtf(vr[c] + 1e-5f);
    a[c] = s;
    dd[c] = (cb[c] - mn[c]) * s + be[c];
  }
}

__global__ void wihcvt_k(const float* __restrict__ S, bf16_t* __restrict__ D) {
  size_t i = ((size_t)blockIdx.x * 256 + threadIdx.x) * 4;
  if (i >= 3ul * 2 * 2048 * 1024) return;
  float4 v = *(const float4*)(S + i);
  bf16_t o[4] = {f2b(v.x), f2b(v.y), f2b(v.z), f2b(v.w)};
  *(uint2*)(D + i) = *(const uint2*)o;
}

// ---------------- gates GEMM: D[m=t*16+b][n=g*512+j] -> G[t][j>>4][g][j&15][b]
__global__ __launch_bounds__(256, 1) void gemm_gates(
    const bf16_t* __restrict__ A, const bf16_t* __restrict__ W,
    const float* __restrict__ bias0, const float* __restrict__ bias1,
    bf16_t* __restrict__ G) {
  const int tid = threadIdx.x;
  const int m0 = (blockIdx.x >> 4) * 128, n0 = (blockIdx.x & 15) * 128;
  __shared__ bf16_t As[128][72];
  __shared__ bf16_t Bs[128][72];
  const int wv = tid >> 6, ln = tid & 63;
  const int wm = (wv >> 1) * 64, wn = (wv & 1) * 64;
  const int lb = ln & 15, lq = ln >> 4;
  f32x4 acc[4][4] = {};
  for (int k0 = 0; k0 < 1024; k0 += 64) {
    __syncthreads();
#pragma unroll
    for (int i = 0; i < 4; i++) {
      int idx = tid + i * 256, r = idx >> 3, ch = idx & 7;
      *(uint4*)&As[r][ch * 8] = *(const uint4*)(A + (size_t)(m0 + r) * 1024 + k0 + ch * 8);
      *(uint4*)&Bs[r][ch * 8] = *(const uint4*)(W + (size_t)(n0 + r) * 1024 + k0 + ch * 8);
    }
    __syncthreads();
#pragma unroll
    for (int kk = 0; kk < 2; kk++) {
      bf16x8 af[4], bfr[4];
#pragma unroll
      for (int t = 0; t < 4; t++) {
        af[t]  = *(const bf16x8*)&As[wm + t * 16 + lb][kk * 32 + lq * 8];
        bfr[t] = *(const bf16x8*)&Bs[wn + t * 16 + lb][kk * 32 + lq * 8];
      }
#pragma unroll
      for (int mt = 0; mt < 4; mt++)
#pragma unroll
        for (int nt = 0; nt < 4; nt++)
          acc[mt][nt] = __builtin_amdgcn_mfma_f32_16x16x32_bf16(af[mt], bfr[nt], acc[mt][nt], 0, 0, 0);
    }
  }
#pragma unroll
  for (int mt = 0; mt < 4; mt++)
#pragma unroll
    for (int nt = 0; nt < 4; nt++) {
      int col = n0 + wn + nt * 16 + lb;          // g*512 + j
      int g = col >> 9, j = col & 511;
      int jb2 = j >> 4, jp = j & 15;
      float bs = bias0[col] + bias1[col];
      int row0 = m0 + wm + mt * 16;              // t*16, b = lq*4 + r
      int t = row0 >> 4;
      bf16_t tmp[4];
#pragma unroll
      for (int r = 0; r < 4; r++) tmp[r] = f2b(acc[mt][nt][r] + bs);
      size_t base = (((size_t)t * 32 + jb2) * 4 + g) * 256 + jp * 16 + lq * 4;
      *(uint2*)&G[base] = *(const uint2*)tmp;    // 4 consecutive b, 8B store
    }
}

// ---------------- conv1d implicit GEMM + BN + ReLU
__global__ __launch_bounds__(256, 1) void conv_gemm(
    const bf16_t* __restrict__ EP, const bf16_t* __restrict__ Wc,
    const float* __restrict__ bn_a, const float* __restrict__ bn_d,
    bf16_t* __restrict__ X) {
  const int tid = threadIdx.x;
  const int m0 = (blockIdx.x >> 3) * 128, n0 = (blockIdx.x & 7) * 128;
  __shared__ bf16_t As[128][72];
  __shared__ bf16_t Bs[128][72];
  const int wv = tid >> 6, ln = tid & 63;
  const int wm = (wv >> 1) * 64, wn = (wv & 1) * 64;
  const int lb = ln & 15, lq = ln >> 4;
  f32x4 acc[4][4] = {};
  for (int kk = 0; kk < 5; kk++) {
    for (int k0 = 0; k0 < 1024; k0 += 64) {
      __syncthreads();
#pragma unroll
      for (int i = 0; i < 4; i++) {
        int idx = tid + i * 256, r = idx >> 3, ch = idx & 7;
        int m = m0 + r;
        const bf16_t* ap = EP + ((size_t)((m & 15) * 1028 + (m >> 4) + kk)) * 1024 + k0 + ch * 8;
        *(uint4*)&As[r][ch * 8] = *(const uint4*)ap;
        *(uint4*)&Bs[r][ch * 8] = *(const uint4*)(Wc + (size_t)(n0 + r) * 5120 + kk * 1024 + k0 + ch * 8);
      }
      __syncthreads();
#pragma unroll
      for (int kq = 0; kq < 2; kq++) {
        bf16x8 af[4], bfr[4];
#pragma unroll
        for (int t = 0; t < 4; t++) {
          af[t]  = *(const bf16x8*)&As[wm + t * 16 + lb][kq * 32 + lq * 8];
          bfr[t] = *(const bf16x8*)&Bs[wn + t * 16 + lb][kq * 32 + lq * 8];
        }
#pragma unroll
        for (int mt = 0; mt < 4; mt++)
#pragma unroll
          for (int nt = 0; nt < 4; nt++)
            acc[mt][nt] = __builtin_amdgcn_mfma_f32_16x16x32_bf16(af[mt], bfr[nt], acc[mt][nt], 0, 0, 0);
      }
    }
  }
#pragma unroll
  for (int mt = 0; mt < 4; mt++)
#pragma unroll
    for (int nt = 0; nt < 4; nt++) {
      int col = n0 + wn + nt * 16 + lb;
      float sa = bn_a[col], sd = bn_d[col];
#pragma unroll
      for (int r = 0; r < 4; r++) {
        int row = m0 + wm + mt * 16 + lq * 4 + r;
        float v = fmaxf(acc[mt][nt][r] * sa + sd, 0.f);
        X[(size_t)row * 1024 + col] = f2b(v);
      }
    }
}

// ---------------- persistent BiLSTM recurrence
// grid = 64 WGs: dir = blk>>5, j0 = (blk&31)*16. 256 thr = 4 waves (wave=gate).
// hstT: [2buf][2dir][256 pair][16 b] u64 = (tag<<32)|2xbf16.
__global__ __launch_bounds__(256, 1) void rec_kernel(
    const float* __restrict__ Whh,               // [2][2048][512] f32
    const bf16_t* __restrict__ Gfw,              // [512 t][32 jb][4 g][16 j'][16 b]
    const bf16_t* __restrict__ Gbw,
    bf16_t* __restrict__ xout,                   // [1024][16][1024]
    unsigned long long* __restrict__ hstT,
    float* __restrict__ cst,                     // [2dir][16][512]
    int t0f, int t0b, int nsteps, int tag_base) {
  const int tid = threadIdx.x;
  const int d  = blockIdx.x >> 5;
  const int j0 = (blockIdx.x & 31) << 4;
  const int wv = tid >> 6;
  const int ln = tid & 63;
  const int lb = ln & 15;
  const int lq = ln >> 4;

  __shared__ bf16_t Hb[16][522];        // 261 dw row stride (==5 mod 32)
  __shared__ float  Ex[4][16][17];
  __shared__ bf16_t Gs[2][1024];        // gate slice double buffer (2KB each)
  __shared__ bf16_t XB[16][16][16];     // xout buffer [t'][b][j']

  // A fragments: wave wv = gate; row lb -> Whh[d*2048 + wv*512 + j0 + lb]
  bf16x8 afrag[16];
  {
    const float* wrow = Whh + ((size_t)(d * 2048 + wv * 512 + j0 + lb)) * 512;
#pragma unroll
    for (int kk = 0; kk < 16; kk++) {
      const float* wp = wrow + kk * 32 + lq * 8;
      float4 va = *(const float4*)wp;
      float4 vb = *(const float4*)(wp + 4);
      bf16x8 fr;
      fr[0] = f2b(va.x); fr[1] = f2b(va.y); fr[2] = f2b(va.z); fr[3] = f2b(va.w);
      fr[4] = f2b(vb.x); fr[5] = f2b(vb.y); fr[6] = f2b(vb.z); fr[7] = f2b(vb.w);
      afrag[kk] = fr;
    }
  }
  const int cb = tid & 15;      // batch  (swapped vs R3 for coalesced stores)
  const int cj = tid >> 4;      // j unit
  float creg = cst[((size_t)d * 16 + cb) * 512 + j0 + cj];
  const bf16_t* G = (d == 0) ? Gfw : Gbw;
  const int jblk = j0 >> 4;

  // preload gate slice for s=0 into Gs[0]
  {
    const int trow = (d == 0) ? 0 : (nsteps - 1);
    uint2 g0 = *(const uint2*)(G + ((size_t)trow * 32 + jblk) * 1024 + tid * 4);
    *(uint2*)&Gs[0][tid * 4] = g0;
  }

  for (int s = 0; s < nsteps; s++) {
    const int rb = (s & 1) ^ 1, wb = s & 1;
    const int t = (d == 0) ? (t0f + s) : (t0b + nsteps - 1 - s);
    // issue next step's gate load BEFORE the poll (latency hides under poll RT)
    uint2 gnext = {0, 0};
    if (s + 1 < nsteps) {
      const int trn = (d == 0) ? (s + 1) : (nsteps - 2 - s);
      gnext = *(const uint2*)(G + ((size_t)trn * 32 + jblk) * 1024 + tid * 4);
    }
    // tagged poll: wave wv owns qwords [wv*1024, wv*1024+1024)
    {
      const unsigned long long* src =
          hstT + ((size_t)rb * 2 + d) * 4096 + (wv << 10);
      const unsigned expect = (unsigned)(tag_base + s);
      unsigned long long v[16];
      bool ok;
      do {
        ok = true;
#pragma unroll
        for (int i = 0; i < 16; i++)
          v[i] = __hip_atomic_load(src + i * 64 + ln, __ATOMIC_RELAXED, __HIP_MEMORY_SCOPE_AGENT);
#pragma unroll
        for (int i = 0; i < 16; i++) ok = ok && ((unsigned)(v[i] >> 32) == expect);
      } while (!__all(ok));
      // qword q = wv*1024 + i*64 + ln -> pair = q>>4 = wv*64 + i*4 + lq, b = lb
#pragma unroll
      for (int i = 0; i < 16; i++) {
        int pair = (wv << 6) + i * 4 + lq;
        *(unsigned*)&Hb[lb][pair * 2] = (unsigned)v[i];
      }
    }
    __syncthreads();
    f32x4 acc0 = {}, acc1 = {};
#pragma unroll
    for (int kk = 0; kk < 8; kk++) {
      bf16x8 b0 = *(const bf16x8*)&Hb[lb][(2 * kk) * 32 + lq * 8];
      bf16x8 b1 = *(const bf16x8*)&Hb[lb][(2 * kk + 1) * 32 + lq * 8];
      acc0 = __builtin_amdgcn_mfma_f32_16x16x32_bf16(afrag[2 * kk], b0, acc0, 0, 0, 0);
      acc1 = __builtin_amdgcn_mfma_f32_16x16x32_bf16(afrag[2 * kk + 1], b1, acc1, 0, 0, 0);
    }
#pragma unroll
    for (int r = 0; r < 4; r++) Ex[wv][lq * 4 + r][lb] = acc0[r] + acc1[r];
    __syncthreads();
    // cell: thread -> (batch cb, unit j0+cj); gates from LDS slice
    const bf16_t* gs = &Gs[s & 1][0];
    float gi = Ex[0][cj][cb] + b2f(gs[0 * 256 + cj * 16 + cb]);
    float gf = Ex[1][cj][cb] + b2f(gs[1 * 256 + cj * 16 + cb]);
    float gg = Ex[2][cj][cb] + b2f(gs[2 * 256 + cj * 16 + cb]);
    float go = Ex[3][cj][cb] + b2f(gs[3 * 256 + cj * 16 + cb]);
    float si = 1.f / (1.f + expf(-gi));
    float sf = 1.f / (1.f + expf(-gf));
    float so = 1.f / (1.f + expf(-go));
    creg = sf * creg + si * tanhf(gg);
    float h = so * tanhf(creg);
    bf16_t hb = f2b(h);
    XB[t & 15][cb][cj] = hb;
    if (s + 1 < nsteps) *(uint2*)&Gs[(s + 1) & 1][tid * 4] = gnext;
    // h pair (j even with j+1 from lane+16) -> coalesced 8B tagged atomics
    {
      unsigned hu = (unsigned)(unsigned short)hb;
      unsigned hp = (unsigned)__shfl_down((int)hu, 16, 64);
      if ((cj & 1) == 0) {
        unsigned data = hu | (hp << 16);
        unsigned long long val =
            ((unsigned long long)(unsigned)(tag_base + s + 1) << 32) | data;
        unsigned long long* dst =
            hstT + ((size_t)wb * 2 + d) * 4096 + (size_t)((j0 + cj) >> 1) * 16 + cb;
        __hip_atomic_store(dst, val, __ATOMIC_RELAXED, __HIP_MEMORY_SCOPE_AGENT);
      }
    }
    // xout flush every 16 steps (coalesced-ish 32B chunks, amortized)
    if ((s & 15) == 15) {
      __syncthreads();
      const int tbase = (d == 0) ? (t - 15) : t;   // 16-aligned in both dirs
      const int tt = tbase + (tid >> 4);
      const int b  = tid & 15;
      const bf16_t* xb = &XB[tid >> 4][b][0];
      bf16_t* xo = xout + ((size_t)tt * 16 + b) * 1024 + d * 512 + j0;
      *(uint4*)xo = *(const uint4*)xb;
      *(uint4*)(xo + 8) = *(const uint4*)(xb + 8);
    }
  }
  cst[((size_t)d * 16 + cb) * 512 + j0 + cj] = creg;
}

// ---------------- classifier
__global__ void cls_kernel(const bf16_t* __restrict__ X, const float* __restrict__ Wc,
                           const float* __restrict__ bc, float* __restrict__ Lg) {
  int wv = threadIdx.x >> 6, ln = threadIdx.x & 63;
  size_t m = (size_t)blockIdx.x * 4 + wv;
  const bf16_t* xr = X + m * 1024 + ln * 16;
  uint4 v0 = *(const uint4*)xr;
  uint4 v1 = *(const uint4*)(xr + 8);
  float xv[16];
  const unsigned* p0 = (const unsigned*)&v0;
  const unsigned* p1 = (const unsigned*)&v1;
#pragma unroll
  for (int i = 0; i < 4; i++) { xv[2 * i] = blo(p0[i]); xv[2 * i + 1] = bhi(p0[i]); }
#pragma unroll
  for (int i = 0; i < 4; i++) { xv[8 + 2 * i] = blo(p1[i]); xv[8 + 2 * i + 1] = bhi(p1[i]); }
#pragma unroll
  for (int l = 0; l < 6; l++) {
    const float* wr = Wc + l * 1024 + ln * 16;
    float p = 0.f;
#pragma unroll
    for (int i = 0; i < 16; i++) p += xv[i] * wr[i];
#pragma unroll
    for (int off = 32; off; off >>= 1) p += __shfl_xor(p, off, 64);
    if (ln == 0) Lg[m * 6 + l] = p + bc[l];
  }
}

// ---------------- CRF NLL
__global__ void crf_kernel(const float* __restrict__ Lg, const int* __restrict__ attn,
                           const int* __restrict__ labels, const float* __restrict__ start,
                           const float* __restrict__ endw, const float* __restrict__ trans,
                           float* __restrict__ out) {
  int b = blockIdx.x, ln = threadIdx.x;
  __shared__ float str[36];
  __shared__ int tg[1024];
  __shared__ unsigned char mk[1024];
  if (ln < 36) str[ln] = trans[ln];
  for (int t = ln; t < 1024; t += 64) {
    int lab = labels[b * 1024 + t];
    mk[t] = (unsigned char)((attn[b * 1024 + t] != 0) && (lab != -100));
    tg[t] = (lab == -100) ? 0 : lab;
  }
  __syncthreads();
  int j = ln;
  bool act = j < 6;
  float alpha = act ? (start[j] + Lg[(size_t)b * 6 + j]) : -1e30f;
  for (int t = 1; t < 1024; t++) {
    float vv[6], mx = -1e30f;
#pragma unroll
    for (int i = 0; i < 6; i++) {
      float ai = __shfl(alpha, i, 64);
      float v = ai + str[i * 6 + (act ? j : 0)];
      vv[i] = v;
      mx = fmaxf(mx, v);
    }
    float sm = 0.f;
#pragma unroll
    for (int i = 0; i < 6; i++) sm += expf(vv[i] - mx);
    float na = mx + logf(sm) + (act ? Lg[((size_t)t * 16 + b) * 6 + j] : 0.f);
    if (mk[t] && act) alpha = na;
  }
  float z = act ? (alpha + endw[j]) : -1e30f;
  float zm = z;
#pragma unroll
  for (int i = 0; i < 6; i++) zm = fmaxf(zm, __shfl(z, i, 64));
  float zs = act ? expf(z - zm) : 0.f;
  float tot = 0.f;
#pragma unroll
  for (int i = 0; i < 6; i++) tot += __shfl(zs, i, 64);
  float den = zm + logf(tot);
  if (ln == 0) {
    float score = start[tg[0]] + Lg[(size_t)b * 6 + tg[0]];
    int prev = tg[0];
    for (int t = 1; t < 1024; t++) {
      if (mk[t]) {
        score += str[prev * 6 + tg[t]] + Lg[((size_t)t * 16 + b) * 6 + tg[t]];
        prev = tg[t];
      }
    }
    score += endw[prev];
    atomicAdd(out, (den - score) * (1.0f / 16.0f));
  }
}

// ---------------------------------------------------------------------------
extern "C" void kernel_launch(void* const* d_in, const int* in_sizes, int n_in,
                              void* d_out, int out_size, void* d_ws, size_t ws_size,
                              hipStream_t stream) {
  const float* emb    = (const float*)d_in[0];
  const int*   attn   = (const int*)d_in[1];
  const int*   labels = (const int*)d_in[2];
  const float* convw  = (const float*)d_in[3];
  const float* convb  = (const float*)d_in[4];
  const float* bng    = (const float*)d_in[5];
  const float* bnb    = (const float*)d_in[6];
  const float* bnm    = (const float*)d_in[7];
  const float* bnv    = (const float*)d_in[8];
  const float* wih    = (const float*)d_in[9];
  const float* whh    = (const float*)d_in[10];
  const float* bih    = (const float*)d_in[11];
  const float* bhh    = (const float*)d_in[12];
  const float* clsw   = (const float*)d_in[13];
  const float* clsb   = (const float*)d_in[14];
  const float* crfs   = (const float*)d_in[15];
  const float* crfe   = (const float*)d_in[16];
  const float* crft   = (const float*)d_in[17];
  (void)in_sizes; (void)n_in; (void)out_size; (void)ws_size;

  char* w = (char*)d_ws;
  auto alloc = [&](size_t bytes) { char* p = w; w += (bytes + 255) & ~(size_t)255; return p; };
  bf16_t* emb_pad = (bf16_t*)alloc(16ul * 1028 * 1024 * 2);
  bf16_t* wconv   = (bf16_t*)alloc(1024ul * 5120 * 2);
  float*  bn_a    = (float*)alloc(4096);
  float*  bn_d    = (float*)alloc(4096);
  bf16_t* wihb    = (bf16_t*)alloc(3ul * 2 * 2048 * 1024 * 2);
  bf16_t* xA      = (bf16_t*)alloc(16384ul * 1024 * 2);
  bf16_t* xB      = (bf16_t*)alloc(16384ul * 1024 * 2);
  bf16_t* gfw     = (bf16_t*)alloc(512ul * 32 * 1024 * 2);
  bf16_t* gbw     = (bf16_t*)alloc(512ul * 32 * 1024 * 2);
  unsigned long long* hstT = (unsigned long long*)alloc(2ul * 2 * 4096 * 8);
  float*  cst     = (float*)alloc(2ul * 16 * 512 * 4);
  float*  lgt     = (float*)alloc(16384ul * 6 * 4);

  hipMemsetAsync(d_out, 0, 4, stream);

  embed_pad_k<<<16448, 256, 0, stream>>>(emb, emb_pad);
  convw_cvt_k<<<4096, 256, 0, stream>>>(convw, wconv);
  bnfold_k<<<4, 256, 0, stream>>>(convb, bng, bnb, bnm, bnv, bn_a, bn_d);
  wihcvt_k<<<12288, 256, 0, stream>>>(wih, wihb);

  conv_gemm<<<128 * 8, 256, 0, stream>>>(emb_pad, wconv, bn_a, bn_d, xA);

  bf16_t* xin = xA;
  bf16_t* xout = xB;
  for (int l = 0; l < 3; l++) {
    hipMemsetAsync(hstT, 0, 2ul * 2 * 4096 * 8, stream);
    hipMemsetAsync(cst, 0, 2ul * 16 * 512 * 4, stream);
    for (int c = 0; c < 2; c++) {
      int t0f = c * 512, t0b = (1 - c) * 512;
      gemm_gates<<<64 * 16, 256, 0, stream>>>(
          xin + (size_t)t0f * 16 * 1024, wihb + ((size_t)l * 2 + 0) * 2048 * 1024,
          bih + (l * 2 + 0) * 2048, bhh + (l * 2 + 0) * 2048, gfw);
      gemm_gates<<<64 * 16, 256, 0, stream>>>(
          xin + (size_t)t0b * 16 * 1024, wihb + ((size_t)l * 2 + 1) * 2048 * 1024,
          bih + (l * 2 + 1) * 2048, bhh + (l * 2 + 1) * 2048, gbw);
      rec_kernel<<<64, 256, 0, stream>>>(whh + (size_t)l * 2 * 2048 * 512,
                                         gfw, gbw, xout, hstT, cst, t0f, t0b, 512, c * 512);
    }
    bf16_t* tmp = xin; xin = xout; xout = tmp;
  }

  cls_kernel<<<4096, 256, 0, stream>>>(xin, clsw, clsb, lgt);
  crf_kernel<<<16, 64, 0, stream>>>(lgt, attn, labels, crfs, crfe, crft, (float*)d_out);
}